// Round 1
// 596.825 us; speedup vs baseline: 1.0961x; 1.0961x over previous
//
#include <hip/hip_runtime.h>
#include <math.h>

#define NB 64
#define NN 4096
#define NF 256
#define NC 10
#define NSPLIT 16
#define CH 256            // rows per split
#define LW 263            // LDS tile pitch (floats) — odd → conflict-free transposed reads
#define EMPTYK 0xFFFFFFFFu

// ---------------------------------------------------------------- K1: streaming stats + transpose
// v3: register-prefetch software pipeline + reader-side stats.
//   phase 1: clean (NaN->0, -0->+0) prefetched tile, ds_write into skewed LDS tile.
//   phase 2: issue next tile's 8 float4 loads FIRST (stay in flight across the whole
//            phase + barriers), then transpose write-out to XT, then per-feature stats
//            from conflict-free transposed LDS reads (thread t owns feature t).
//   The old 4-phase red[] cross-wave reduction (64-way bank conflicts) is gone:
//   each thread holds feature-complete partials and writes P directly.
__global__ __launch_bounds__(256, 4) void k_stats(const float* __restrict__ X,
                                                  const int* __restrict__ Y,
                                                  unsigned* __restrict__ XT,
                                                  float* __restrict__ P) {
  __shared__ unsigned ldsT[32 * LW];  // 33,664 B -> 4 blocks/CU
  const int bi = blockIdx.x;
  const int b = bi >> 4, sp = bi & 15;
  const int t = threadIdx.x;
  const int w = t >> 6, l = t & 63;
  const int n0 = sp * CH;
  const float4* Xv = (const float4*)X;

  // Y chunk preload: lane l of every wave holds rows n0+{l, 64+l, 128+l, 192+l}
  const int y0 = Y[b * NN + n0 + l];
  const int y1 = Y[b * NN + n0 + 64 + l];
  const int y2 = Y[b * NN + n0 + 128 + l];
  const int y3 = Y[b * NN + n0 + 192 + l];

  // per-feature (f = t) accumulators — reader side
  float s1 = 0.f, s2 = 0.f, sab = 0.f, mab = 0.f;
  float cls[NC] = {};
  // writer-side NaN counts for features 4l..4l+3 over rows ≡ w (mod 4)
  float nanc4[4] = {0.f, 0.f, 0.f, 0.f};

  const int colbase = 4 * l + (l >> 3);
  const int myoff = t + (t >> 5);   // skewed column offset of feature t

  float4 pf[8];
#pragma unroll
  for (int it = 0; it < 8; ++it) {  // prime tile 0
    const int n = n0 + it * 4 + w;
    pf[it] = Xv[(size_t)(b * NN + n) * (NF / 4) + l];
  }

  for (int tile = 0; tile < 8; ++tile) {
    // ---- phase 1: clean + LDS write (consumes pf)
#pragma unroll
    for (int it = 0; it < 8; ++it) {
      const float v[4] = {pf[it].x, pf[it].y, pf[it].z, pf[it].w};
      const int lb = (it * 4 + w) * LW + colbase;
#pragma unroll
      for (int q = 0; q < 4; ++q) {
        float c = v[q];
        if (c != c) { nanc4[q] += 1.f; c = 0.f; }          // nan_to_num(nan=0)
        ldsT[lb + q] = (c == 0.f) ? 0u : __float_as_uint(c);  // -0 -> +0
      }
    }
    __syncthreads();

    // ---- phase 2a: prefetch next tile into regs (in flight across everything below)
    if (tile < 7) {
#pragma unroll
      for (int it = 0; it < 8; ++it) {
        const int n = n0 + (tile + 1) * 32 + it * 4 + w;
        pf[it] = Xv[(size_t)(b * NN + n) * (NF / 4) + l];
      }
    }

    // ---- phase 2b: transposed write-out (8 threads cooperate per feature → 128B segments)
#pragma unroll
    for (int j = 0; j < 8; ++j) {
      const int idx = t + 256 * j;
      const int f = idx >> 3, rr4 = idx & 7;
      const int fo = f + (f >> 5);
      uint4 o;
      o.x = ldsT[(rr4 * 4 + 0) * LW + fo];
      o.y = ldsT[(rr4 * 4 + 1) * LW + fo];
      o.z = ldsT[(rr4 * 4 + 2) * LW + fo];
      o.w = ldsT[(rr4 * 4 + 3) * LW + fo];
      ((uint4*)(XT + (size_t)(b * NF + f) * NN + n0 + tile * 32))[rr4] = o;
    }

    // ---- phase 2c: stats for feature t over this tile's 32 rows (2-way reads = free)
    const int kk = tile >> 1;
    const int yl = (kk & 2) ? ((kk & 1) ? y3 : y2) : ((kk & 1) ? y1 : y0);
    const int lbase = (tile & 1) * 32;
#pragma unroll
    for (int r = 0; r < 32; ++r) {
      const float c = __uint_as_float(ldsT[r * LW + myoff]);
      const int y = __builtin_amdgcn_readlane(yl, lbase + r);  // wave-uniform
      s1 += c;
      s2 = fmaf(c, c, s2);
      const float a = fabsf(c);
      sab += a;
      mab = fmaxf(mab, a);
      switch (y) {
        case 0: cls[0] += c; break; case 1: cls[1] += c; break;
        case 2: cls[2] += c; break; case 3: cls[3] += c; break;
        case 4: cls[4] += c; break; case 5: cls[5] += c; break;
        case 6: cls[6] += c; break; case 7: cls[7] += c; break;
        case 8: cls[8] += c; break; case 9: cls[9] += c; break;
        default: break;
      }
    }
    __syncthreads();
  }

  // NaN-count redistribution (writer-side 4-feat counts -> reader-side feature t)
  float* nl = (float*)ldsT;
#pragma unroll
  for (int q = 0; q < 4; ++q) nl[w * 256 + 4 * l + q] = nanc4[q];
  __syncthreads();
  const float nanc = nl[t] + nl[256 + t] + nl[512 + t] + nl[768 + t];

  float vals[16];
  vals[0] = s1; vals[1] = s2; vals[2] = sab; vals[3] = mab; vals[4] = nanc;
#pragma unroll
  for (int c = 0; c < NC; ++c) vals[5 + c] = cls[c];
  vals[15] = 0.f;
  float4* Pv = (float4*)(P + ((size_t)(b * NSPLIT + sp) * NF + t) * 16);
  Pv[0] = *(float4*)&vals[0];
  Pv[1] = *(float4*)&vals[4];
  Pv[2] = *(float4*)&vals[8];
  Pv[3] = *(float4*)&vals[12];
}

// ---------------------------------------------------------------- K3: exact distinct count per column
// atomic-free race-tolerant multi-level dedup (unchanged scheme); terminal-level
// table clear is now skipped (32 KB of LDS stores per block saved on the last level).
__global__ __launch_bounds__(256) void k_uniq(const unsigned* __restrict__ XT,
                                              unsigned* __restrict__ uniq) {
  __shared__ unsigned tab[8192];   // 32,768 B exactly → 5 blocks/CU
  const int t = threadIdx.x;
  const size_t base = (size_t)blockIdx.x * NN;

  // issue global loads first so they overlap table init
  const uint4* Xv = (const uint4*)(XT + base);
  uint4 kv0 = Xv[t], kv1 = Xv[256 + t], kv2 = Xv[512 + t], kv3 = Xv[768 + t];

  uint4* tv = (uint4*)tab;
  const uint4 e4 = make_uint4(EMPTYK, EMPTYK, EMPTYK, EMPTYK);
#pragma unroll
  for (int i = 0; i < 8; ++i) tv[t + 256 * i] = e4;

  unsigned key[16] = {kv0.x, kv0.y, kv0.z, kv0.w, kv1.x, kv1.y, kv1.z, kv1.w,
                      kv2.x, kv2.y, kv2.z, kv2.w, kv3.x, kv3.y, kv3.z, kv3.w};
  unsigned h[16];
#pragma unroll
  for (int q = 0; q < 16; ++q) h[q] = (key[q] * 2654435761u) >> 19;  // 13 bits
  unsigned pend = 0xFFFFu;
  unsigned salt = 0x9E3779B9u;
  int cnt = 0;
  __syncthreads();

  while (true) {
    // write pass (plain stores; racing word-writes resolve to one winner value)
#pragma unroll
    for (int q = 0; q < 16; ++q)
      if (pend & (1u << q)) tab[h[q]] = key[q];
    __syncthreads();
    // read-back classify
#pragma unroll
    for (int q = 0; q < 16; ++q)
      if (pend & (1u << q)) {
        if (tab[h[q]] == key[q]) pend &= ~(1u << q);
        else h[q] = ((key[q] ^ salt) * 2654435761u) >> 19;  // fresh hash next level
      }
    salt += 0x9E3779B9u;
    const int live = __syncthreads_count(pend != 0);  // orders classify-reads before clear
    // scan own exclusive slice: count claims; clear only if another level follows
#pragma unroll
    for (int i = 0; i < 8; ++i) {
      uint4 v = tv[t + 256 * i];
      cnt += (v.x != EMPTYK) + (v.y != EMPTYK) + (v.z != EMPTYK) + (v.w != EMPTYK);
      if (live) tv[t + 256 * i] = e4;
    }
    if (!live) break;
    __syncthreads();                 // clear visible before next write pass
  }

  for (int off = 32; off; off >>= 1) cnt += __shfl_down(cnt, off, 64);
  __syncthreads();                  // table idle; reuse for cross-wave partials
  if ((t & 63) == 0) tab[t >> 6] = (unsigned)cnt;
  __syncthreads();
  if (t == 0) uniq[blockIdx.x] = tab[0] + tab[1] + tab[2] + tab[3];
}

// ---------------------------------------------------------------- K2: reduce partials → 6 stats
// now also computes the per-batch class histogram (k_counts folded in): compare-chain
// per-thread counts + wave shuffle-reduce — no atomics.
__global__ __launch_bounds__(256) void k_finalize(const float* __restrict__ P,
                                                  const int* __restrict__ Y,
                                                  const unsigned* __restrict__ uniq,
                                                  float* __restrict__ stats6) {
  __shared__ float whist[4 * NC];
  const int b = blockIdx.x;          // 64 blocks == batches
  const int t = threadIdx.x;

  int cnt[NC];
#pragma unroll
  for (int c = 0; c < NC; ++c) cnt[c] = 0;
#pragma unroll
  for (int i = 0; i < 16; ++i) {
    const int y = Y[b * NN + 256 * i + t];
#pragma unroll
    for (int c = 0; c < NC; ++c) cnt[c] += (y == c) ? 1 : 0;
  }
#pragma unroll
  for (int c = 0; c < NC; ++c) {
    int v = cnt[c];
    for (int off = 32; off; off >>= 1) v += __shfl_down(v, off, 64);
    cnt[c] = v;
  }
  if ((t & 63) == 0) {
#pragma unroll
    for (int c = 0; c < NC; ++c) whist[(t >> 6) * NC + c] = (float)cnt[c];
  }
  __syncthreads();

  const int f = t;
  const int col = b * 256 + f;
  float acc[16];
#pragma unroll
  for (int i = 0; i < 16; ++i) acc[i] = 0.f;
  for (int sp = 0; sp < NSPLIT; ++sp) {
    const float4* p4 = (const float4*)(P + ((size_t)(b * NSPLIT + sp) * NF + f) * 16);
    float4 A = p4[0], B4 = p4[1], C4 = p4[2], D4 = p4[3];
    acc[0] += A.x; acc[1] += A.y; acc[2] += A.z; acc[3] = fmaxf(acc[3], A.w);
    acc[4] += B4.x; acc[5] += B4.y; acc[6] += B4.z; acc[7] += B4.w;
    acc[8] += C4.x; acc[9] += C4.y; acc[10] += C4.z; acc[11] += C4.w;
    acc[12] += D4.x; acc[13] += D4.y; acc[14] += D4.z;
  }
  const float invN = 1.f / (float)NN;
  const float mean = acc[0] * invN;
  float var = acc[1] * invN - mean * mean;
  if (var < 0.f) var = 0.f;
  const float meanabs = acc[2] * invN;
  const float maxabs = acc[3];
  const float miss = acc[4] * invN;
  const float uratio = (float)uniq[col] * invN;
  float btw = 0.f;
#pragma unroll
  for (int c = 0; c < NC; ++c) {
    const float cntc = whist[c] + whist[NC + c] + whist[2 * NC + c] + whist[3 * NC + c];
    const float m = acc[5 + c] / fmaxf(cntc, 1.f);
    const float d = m - mean;
    btw = fmaf(cntc * d, d, btw);
  }
  btw *= invN;  // counts.sum() == N
  const float target = btw / fmaxf(var, 1e-6f);
  float st[6] = {target, miss, uratio, var, meanabs, maxabs};
#pragma unroll
  for (int i = 0; i < 6; ++i)
    if (!(fabsf(st[i]) <= 3.4028235e38f)) st[i] = 0.f;  // nan_to_num(nan/±inf → 0)
#pragma unroll
  for (int i = 0; i < 6; ++i) stats6[(size_t)col * 6 + i] = st[i];
}

// ---------------------------------------------------------------- K4: MLP  gelu(stats@W1+b1)@W2+b2
__global__ __launch_bounds__(256) void k_mlp(const float* __restrict__ stats6,
                                             const float* __restrict__ W1,
                                             const float* __restrict__ b1,
                                             const float* __restrict__ W2,
                                             const float* __restrict__ b2,
                                             float* __restrict__ out) {
  __shared__ float w1s[6 * 64];
  __shared__ float b1s[64];
  __shared__ float w2s[64 * 128];
  __shared__ float b2s[128];
  __shared__ float sts[32 * 6];
  __shared__ float hs[64 * 36];  // pitch 36 keeps float4 reads 16B-aligned
  const int t = threadIdx.x;
  const int cb0 = blockIdx.x * 32;
  for (int i = t; i < 96; i += 256) ((float4*)w1s)[i] = ((const float4*)W1)[i];
  if (t < 64) b1s[t] = b1[t];
  for (int i = t; i < 2048; i += 256) ((float4*)w2s)[i] = ((const float4*)W2)[i];
  if (t < 128) b2s[t] = b2[t];
  if (t < 48) ((float4*)sts)[t] = ((const float4*)(stats6 + (size_t)cb0 * 6))[t];
  __syncthreads();

  const int k = t & 63, cg = t >> 6;
#pragma unroll
  for (int cc = 0; cc < 8; ++cc) {
    const int col = cg + 4 * cc;
    float pre = b1s[k];
#pragma unroll
    for (int s = 0; s < 6; ++s) pre = fmaf(sts[col * 6 + s], w1s[s * 64 + k], pre);
    const float h = 0.5f * pre * (1.f + erff(pre * 0.70710678118654752f));  // exact gelu
    hs[k * 36 + col] = h;
  }
  __syncthreads();

  const int j4 = (t & 31) * 4, c4 = (t >> 5) * 4;
  float4 a[4];
  const float4 bj = *(const float4*)&b2s[j4];
  a[0] = bj; a[1] = bj; a[2] = bj; a[3] = bj;
  for (int kk = 0; kk < 64; ++kk) {
    const float4 wv = *(const float4*)&w2s[kk * 128 + j4];
    const float4 hv = *(const float4*)&hs[kk * 36 + c4];
    const float hc[4] = {hv.x, hv.y, hv.z, hv.w};
#pragma unroll
    for (int ci = 0; ci < 4; ++ci) {
      a[ci].x = fmaf(hc[ci], wv.x, a[ci].x);
      a[ci].y = fmaf(hc[ci], wv.y, a[ci].y);
      a[ci].z = fmaf(hc[ci], wv.z, a[ci].z);
      a[ci].w = fmaf(hc[ci], wv.w, a[ci].w);
    }
  }
#pragma unroll
  for (int ci = 0; ci < 4; ++ci) {
    const int col = cb0 + c4 + ci;
    *(float4*)&out[(size_t)col * 128 + j4] = a[ci];
  }
}

// ---------------------------------------------------------------- launch
extern "C" void kernel_launch(void* const* d_in, const int* in_sizes, int n_in,
                              void* d_out, int out_size, void* d_ws, size_t ws_size,
                              hipStream_t stream) {
  const float* X = (const float*)d_in[0];
  const int* Y = (const int*)d_in[1];
  const float* W1 = (const float*)d_in[2];
  const float* b1 = (const float*)d_in[3];
  const float* W2 = (const float*)d_in[4];
  const float* b2 = (const float*)d_in[5];
  float* out = (float*)d_out;

  // workspace layout (needs ~272.4 MiB; counts region retired but offsets kept)
  char* w = (char*)d_ws;
  unsigned* XT = (unsigned*)w;                          // 268,435,456 B  [B,F,N] cleaned bit patterns
  float* P = (float*)(w + 268435456ull);                //  16,777,216 B  partial stats [B,S,F,16]
  float* stats6 = (float*)(w + 285212672ull);           //     393,216 B  [16384,6]
  unsigned* uniq = (unsigned*)(w + 285608448ull);       //      65,536 B  [16384]

  k_stats<<<NB * NSPLIT, 256, 0, stream>>>(X, Y, XT, P);
  k_uniq<<<NB * NF, 256, 0, stream>>>(XT, uniq);
  k_finalize<<<NB, 256, 0, stream>>>(P, Y, uniq, stats6);
  k_mlp<<<512, 256, 0, stream>>>(stats6, W1, b1, W2, b2, out);
}

// Round 2
// 582.019 us; speedup vs baseline: 1.1240x; 1.0254x over previous
//
#include <hip/hip_runtime.h>
#include <math.h>

#define NB 64
#define NN 4096
#define NF 256
#define NC 10
#define NSPLIT 16
#define CH 256            // rows per split
#define LW 263            // LDS tile pitch (floats) — odd → conflict-free transposed reads
#define USLOTS 4096       // k_uniq hash slots (12-bit)

// ---------------------------------------------------------------- K1: streaming stats + transpose
// v3: register-prefetch software pipeline + reader-side stats.
//   phase 1: clean (NaN->0, -0->+0) prefetched tile, ds_write into skewed LDS tile.
//   phase 2: issue next tile's 8 float4 loads FIRST (stay in flight across the whole
//            phase + barriers), then transpose write-out to XT, then per-feature stats
//            from conflict-free transposed LDS reads (thread t owns feature t).
__global__ __launch_bounds__(256, 4) void k_stats(const float* __restrict__ X,
                                                  const int* __restrict__ Y,
                                                  unsigned* __restrict__ XT,
                                                  float* __restrict__ P) {
  __shared__ unsigned ldsT[32 * LW];  // 33,664 B -> 4 blocks/CU
  const int bi = blockIdx.x;
  const int b = bi >> 4, sp = bi & 15;
  const int t = threadIdx.x;
  const int w = t >> 6, l = t & 63;
  const int n0 = sp * CH;
  const float4* Xv = (const float4*)X;

  // Y chunk preload: lane l of every wave holds rows n0+{l, 64+l, 128+l, 192+l}
  const int y0 = Y[b * NN + n0 + l];
  const int y1 = Y[b * NN + n0 + 64 + l];
  const int y2 = Y[b * NN + n0 + 128 + l];
  const int y3 = Y[b * NN + n0 + 192 + l];

  // per-feature (f = t) accumulators — reader side
  float s1 = 0.f, s2 = 0.f, sab = 0.f, mab = 0.f;
  float cls[NC] = {};
  // writer-side NaN counts for features 4l..4l+3 over rows ≡ w (mod 4)
  float nanc4[4] = {0.f, 0.f, 0.f, 0.f};

  const int colbase = 4 * l + (l >> 3);
  const int myoff = t + (t >> 5);   // skewed column offset of feature t

  float4 pf[8];
#pragma unroll
  for (int it = 0; it < 8; ++it) {  // prime tile 0
    const int n = n0 + it * 4 + w;
    pf[it] = Xv[(size_t)(b * NN + n) * (NF / 4) + l];
  }

  for (int tile = 0; tile < 8; ++tile) {
    // ---- phase 1: clean + LDS write (consumes pf)
#pragma unroll
    for (int it = 0; it < 8; ++it) {
      const float v[4] = {pf[it].x, pf[it].y, pf[it].z, pf[it].w};
      const int lb = (it * 4 + w) * LW + colbase;
#pragma unroll
      for (int q = 0; q < 4; ++q) {
        float c = v[q];
        if (c != c) { nanc4[q] += 1.f; c = 0.f; }          // nan_to_num(nan=0)
        ldsT[lb + q] = (c == 0.f) ? 0u : __float_as_uint(c);  // -0 -> +0
      }
    }
    __syncthreads();

    // ---- phase 2a: prefetch next tile into regs (in flight across everything below)
    if (tile < 7) {
#pragma unroll
      for (int it = 0; it < 8; ++it) {
        const int n = n0 + (tile + 1) * 32 + it * 4 + w;
        pf[it] = Xv[(size_t)(b * NN + n) * (NF / 4) + l];
      }
    }

    // ---- phase 2b: transposed write-out (8 threads cooperate per feature → 128B segments)
#pragma unroll
    for (int j = 0; j < 8; ++j) {
      const int idx = t + 256 * j;
      const int f = idx >> 3, rr4 = idx & 7;
      const int fo = f + (f >> 5);
      uint4 o;
      o.x = ldsT[(rr4 * 4 + 0) * LW + fo];
      o.y = ldsT[(rr4 * 4 + 1) * LW + fo];
      o.z = ldsT[(rr4 * 4 + 2) * LW + fo];
      o.w = ldsT[(rr4 * 4 + 3) * LW + fo];
      ((uint4*)(XT + (size_t)(b * NF + f) * NN + n0 + tile * 32))[rr4] = o;
    }

    // ---- phase 2c: stats for feature t over this tile's 32 rows (2-way reads = free)
    const int kk = tile >> 1;
    const int yl = (kk & 2) ? ((kk & 1) ? y3 : y2) : ((kk & 1) ? y1 : y0);
    const int lbase = (tile & 1) * 32;
#pragma unroll
    for (int r = 0; r < 32; ++r) {
      const float c = __uint_as_float(ldsT[r * LW + myoff]);
      const int y = __builtin_amdgcn_readlane(yl, lbase + r);  // wave-uniform
      s1 += c;
      s2 = fmaf(c, c, s2);
      const float a = fabsf(c);
      sab += a;
      mab = fmaxf(mab, a);
      switch (y) {
        case 0: cls[0] += c; break; case 1: cls[1] += c; break;
        case 2: cls[2] += c; break; case 3: cls[3] += c; break;
        case 4: cls[4] += c; break; case 5: cls[5] += c; break;
        case 6: cls[6] += c; break; case 7: cls[7] += c; break;
        case 8: cls[8] += c; break; case 9: cls[9] += c; break;
        default: break;
      }
    }
    __syncthreads();
  }

  // NaN-count redistribution (writer-side 4-feat counts -> reader-side feature t)
  float* nl = (float*)ldsT;
#pragma unroll
  for (int q = 0; q < 4; ++q) nl[w * 256 + 4 * l + q] = nanc4[q];
  __syncthreads();
  const float nanc = nl[t] + nl[256 + t] + nl[512 + t] + nl[768 + t];

  float vals[16];
  vals[0] = s1; vals[1] = s2; vals[2] = sab; vals[3] = mab; vals[4] = nanc;
#pragma unroll
  for (int c = 0; c < NC; ++c) vals[5 + c] = cls[c];
  vals[15] = 0.f;
  float4* Pv = (float4*)(P + ((size_t)(b * NSPLIT + sp) * NF + t) * 16);
  Pv[0] = *(float4*)&vals[0];
  Pv[1] = *(float4*)&vals[4];
  Pv[2] = *(float4*)&vals[8];
  Pv[3] = *(float4*)&vals[12];
}

// ---------------------------------------------------------------- K3: exact distinct count per column
// v5: claimant-tag dedup — no table scan, no clears, no initialization.
//   Per level: (1) pending keys write-race tab[h]=key. (2) barrier; copies whose
//   readback matches write a 16-bit tag (tid*16+q) to tag[h]; losers rehash.
//   (3) barrier; tag readback == own tag → claim one distinct value.
//   Invariants making init/clears unnecessary:
//     - every slot READ was WRITTEN by the reading thread itself this level;
//     - same value ⇒ same hash sequence ⇒ all copies resolve at the same level,
//       so a stale winner value can never equal a still-pending key.
//   Per-level cost is proportional to PENDING count (L2+ nearly free), unlike the
//   old 64 KB scan+clear per level. 4096 slots (load 1.0): ~63% resolve per level.
//   LDS = 16 KB tab + 8 KB tag = 24 KB -> 6 blocks/CU.
__global__ __launch_bounds__(256) void k_uniq(const unsigned* __restrict__ XT,
                                              unsigned* __restrict__ uniq) {
  __shared__ unsigned tab[USLOTS];          // 16,384 B — value write-race table
  __shared__ unsigned short tag[USLOTS];    //  8,192 B — claimant tags
  const int t = threadIdx.x;
  const size_t base = (size_t)blockIdx.x * NN;

  const uint4* Xv = (const uint4*)(XT + base);
  uint4 kv0 = Xv[t], kv1 = Xv[256 + t], kv2 = Xv[512 + t], kv3 = Xv[768 + t];

  unsigned key[16] = {kv0.x, kv0.y, kv0.z, kv0.w, kv1.x, kv1.y, kv1.z, kv1.w,
                      kv2.x, kv2.y, kv2.z, kv2.w, kv3.x, kv3.y, kv3.z, kv3.w};
  unsigned h[16];
#pragma unroll
  for (int q = 0; q < 16; ++q) h[q] = (key[q] * 2654435761u) >> 20;  // 12 bits
  unsigned pend = 0xFFFFu;
  unsigned salt = 0x9E3779B9u;
  int cnt = 0;

  while (true) {
    // (1) value write-race (plain stores; racing word-writes resolve to one winner)
#pragma unroll
    for (int q = 0; q < 16; ++q)
      if (pend & (1u << q)) tab[h[q]] = key[q];
    __syncthreads();
    // (2) classify: matching copies stake a tag claim; losers rehash for next level
    unsigned match = 0;
#pragma unroll
    for (int q = 0; q < 16; ++q)
      if (pend & (1u << q)) {
        if (tab[h[q]] == key[q]) {
          match |= (1u << q);
          tag[h[q]] = (unsigned short)(t * 16 + q);
        } else {
          h[q] = ((key[q] ^ salt) * 2654435761u) >> 20;
        }
      }
    salt += 0x9E3779B9u;
    __syncthreads();
    // (3) claim: exactly one copy of each resolved value wins the tag race
#pragma unroll
    for (int q = 0; q < 16; ++q)
      if (match & (1u << q))
        cnt += (tag[h[q]] == (unsigned short)(t * 16 + q)) ? 1 : 0;
    pend &= ~match;
    if (__syncthreads_count(pend != 0) == 0) break;  // also orders claims vs next level
  }

  for (int off = 32; off; off >>= 1) cnt += __shfl_down(cnt, off, 64);
  // loop-exit barrier ordered all table traffic; reuse tab for cross-wave partials
  if ((t & 63) == 0) tab[t >> 6] = (unsigned)cnt;
  __syncthreads();
  if (t == 0) uniq[blockIdx.x] = tab[0] + tab[1] + tab[2] + tab[3];
}

// ---------------------------------------------------------------- K2: reduce partials → 6 stats
// also computes the per-batch class histogram (k_counts folded in): compare-chain
// per-thread counts + wave shuffle-reduce — no atomics.
__global__ __launch_bounds__(256) void k_finalize(const float* __restrict__ P,
                                                  const int* __restrict__ Y,
                                                  const unsigned* __restrict__ uniq,
                                                  float* __restrict__ stats6) {
  __shared__ float whist[4 * NC];
  const int b = blockIdx.x;          // 64 blocks == batches
  const int t = threadIdx.x;

  int cnt[NC];
#pragma unroll
  for (int c = 0; c < NC; ++c) cnt[c] = 0;
#pragma unroll
  for (int i = 0; i < 16; ++i) {
    const int y = Y[b * NN + 256 * i + t];
#pragma unroll
    for (int c = 0; c < NC; ++c) cnt[c] += (y == c) ? 1 : 0;
  }
#pragma unroll
  for (int c = 0; c < NC; ++c) {
    int v = cnt[c];
    for (int off = 32; off; off >>= 1) v += __shfl_down(v, off, 64);
    cnt[c] = v;
  }
  if ((t & 63) == 0) {
#pragma unroll
    for (int c = 0; c < NC; ++c) whist[(t >> 6) * NC + c] = (float)cnt[c];
  }
  __syncthreads();

  const int f = t;
  const int col = b * 256 + f;
  float acc[16];
#pragma unroll
  for (int i = 0; i < 16; ++i) acc[i] = 0.f;
  for (int sp = 0; sp < NSPLIT; ++sp) {
    const float4* p4 = (const float4*)(P + ((size_t)(b * NSPLIT + sp) * NF + f) * 16);
    float4 A = p4[0], B4 = p4[1], C4 = p4[2], D4 = p4[3];
    acc[0] += A.x; acc[1] += A.y; acc[2] += A.z; acc[3] = fmaxf(acc[3], A.w);
    acc[4] += B4.x; acc[5] += B4.y; acc[6] += B4.z; acc[7] += B4.w;
    acc[8] += C4.x; acc[9] += C4.y; acc[10] += C4.z; acc[11] += C4.w;
    acc[12] += D4.x; acc[13] += D4.y; acc[14] += D4.z;
  }
  const float invN = 1.f / (float)NN;
  const float mean = acc[0] * invN;
  float var = acc[1] * invN - mean * mean;
  if (var < 0.f) var = 0.f;
  const float meanabs = acc[2] * invN;
  const float maxabs = acc[3];
  const float miss = acc[4] * invN;
  const float uratio = (float)uniq[col] * invN;
  float btw = 0.f;
#pragma unroll
  for (int c = 0; c < NC; ++c) {
    const float cntc = whist[c] + whist[NC + c] + whist[2 * NC + c] + whist[3 * NC + c];
    const float m = acc[5 + c] / fmaxf(cntc, 1.f);
    const float d = m - mean;
    btw = fmaf(cntc * d, d, btw);
  }
  btw *= invN;  // counts.sum() == N
  const float target = btw / fmaxf(var, 1e-6f);
  float st[6] = {target, miss, uratio, var, meanabs, maxabs};
#pragma unroll
  for (int i = 0; i < 6; ++i)
    if (!(fabsf(st[i]) <= 3.4028235e38f)) st[i] = 0.f;  // nan_to_num(nan/±inf → 0)
#pragma unroll
  for (int i = 0; i < 6; ++i) stats6[(size_t)col * 6 + i] = st[i];
}

// ---------------------------------------------------------------- K4: MLP  gelu(stats@W1+b1)@W2+b2
__global__ __launch_bounds__(256) void k_mlp(const float* __restrict__ stats6,
                                             const float* __restrict__ W1,
                                             const float* __restrict__ b1,
                                             const float* __restrict__ W2,
                                             const float* __restrict__ b2,
                                             float* __restrict__ out) {
  __shared__ float w1s[6 * 64];
  __shared__ float b1s[64];
  __shared__ float w2s[64 * 128];
  __shared__ float b2s[128];
  __shared__ float sts[32 * 6];
  __shared__ float hs[64 * 36];  // pitch 36 keeps float4 reads 16B-aligned
  const int t = threadIdx.x;
  const int cb0 = blockIdx.x * 32;
  for (int i = t; i < 96; i += 256) ((float4*)w1s)[i] = ((const float4*)W1)[i];
  if (t < 64) b1s[t] = b1[t];
  for (int i = t; i < 2048; i += 256) ((float4*)w2s)[i] = ((const float4*)W2)[i];
  if (t < 128) b2s[t] = b2[t];
  if (t < 48) ((float4*)sts)[t] = ((const float4*)(stats6 + (size_t)cb0 * 6))[t];
  __syncthreads();

  const int k = t & 63, cg = t >> 6;
#pragma unroll
  for (int cc = 0; cc < 8; ++cc) {
    const int col = cg + 4 * cc;
    float pre = b1s[k];
#pragma unroll
    for (int s = 0; s < 6; ++s) pre = fmaf(sts[col * 6 + s], w1s[s * 64 + k], pre);
    const float h = 0.5f * pre * (1.f + erff(pre * 0.70710678118654752f));  // exact gelu
    hs[k * 36 + col] = h;
  }
  __syncthreads();

  const int j4 = (t & 31) * 4, c4 = (t >> 5) * 4;
  float4 a[4];
  const float4 bj = *(const float4*)&b2s[j4];
  a[0] = bj; a[1] = bj; a[2] = bj; a[3] = bj;
  for (int kk = 0; kk < 64; ++kk) {
    const float4 wv = *(const float4*)&w2s[kk * 128 + j4];
    const float4 hv = *(const float4*)&hs[kk * 36 + c4];
    const float hc[4] = {hv.x, hv.y, hv.z, hv.w};
#pragma unroll
    for (int ci = 0; ci < 4; ++ci) {
      a[ci].x = fmaf(hc[ci], wv.x, a[ci].x);
      a[ci].y = fmaf(hc[ci], wv.y, a[ci].y);
      a[ci].z = fmaf(hc[ci], wv.z, a[ci].z);
      a[ci].w = fmaf(hc[ci], wv.w, a[ci].w);
    }
  }
#pragma unroll
  for (int ci = 0; ci < 4; ++ci) {
    const int col = cb0 + c4 + ci;
    *(float4*)&out[(size_t)col * 128 + j4] = a[ci];
  }
}

// ---------------------------------------------------------------- launch
extern "C" void kernel_launch(void* const* d_in, const int* in_sizes, int n_in,
                              void* d_out, int out_size, void* d_ws, size_t ws_size,
                              hipStream_t stream) {
  const float* X = (const float*)d_in[0];
  const int* Y = (const int*)d_in[1];
  const float* W1 = (const float*)d_in[2];
  const float* b1 = (const float*)d_in[3];
  const float* W2 = (const float*)d_in[4];
  const float* b2 = (const float*)d_in[5];
  float* out = (float*)d_out;

  // workspace layout (~272.4 MiB)
  char* w = (char*)d_ws;
  unsigned* XT = (unsigned*)w;                          // 268,435,456 B  [B,F,N] cleaned bit patterns
  float* P = (float*)(w + 268435456ull);                //  16,777,216 B  partial stats [B,S,F,16]
  float* stats6 = (float*)(w + 285212672ull);           //     393,216 B  [16384,6]
  unsigned* uniq = (unsigned*)(w + 285608448ull);       //      65,536 B  [16384]

  k_stats<<<NB * NSPLIT, 256, 0, stream>>>(X, Y, XT, P);
  k_uniq<<<NB * NF, 256, 0, stream>>>(XT, uniq);
  k_finalize<<<NB, 256, 0, stream>>>(P, Y, uniq, stats6);
  k_mlp<<<512, 256, 0, stream>>>(stats6, W1, b1, W2, b2, out);
}